// Round 21
// baseline (234.501 us; speedup 1.0000x reference)
//
#include <hip/hip_runtime.h>

typedef short bf16x8 __attribute__((ext_vector_type(8)));
typedef float f32x4 __attribute__((ext_vector_type(4)));
typedef long i64frag;

#define MFMA16(a, b, c) __builtin_amdgcn_mfma_f32_16x16x32_bf16((a), (b), (c), 0, 0, 0)
#define MFMA8(a, b, c) __builtin_amdgcn_mfma_f32_16x16x32_fp8_fp8((a), (b), (c), 0, 0, 0)

#define SEQ 4096
#define CD 512

#define LGKM0 asm volatile("s_waitcnt lgkmcnt(0)" ::: "memory")
#define VM0   asm volatile("s_waitcnt vmcnt(0)" ::: "memory")
#define VMC12 asm volatile("s_waitcnt vmcnt(12)" ::: "memory")

__device__ __forceinline__ unsigned short f2bf(float f) {
  unsigned u = __builtin_bit_cast(unsigned, f);
  u = u + 0x7FFFu + ((u >> 16) & 1u);
  return (unsigned short)(u >> 16);
}

// pack 4 floats -> 4 OCP e4m3 bytes (gfx950 HW cvt)
__device__ __forceinline__ int pk4_fp8(float p0, float p1, float p2, float p3) {
  int w = __builtin_amdgcn_cvt_pk_fp8_f32(p0, p1, 0, false);
  w = __builtin_amdgcn_cvt_pk_fp8_f32(p2, p3, w, true);
  return w;
}

__device__ __forceinline__ void gload_lds16(const void* g, void* l) {
  __builtin_amdgcn_global_load_lds(
      (const __attribute__((address_space(1))) void*)g,
      (__attribute__((address_space(3))) void*)l, 16, 0, 0);
}

// ---------------- weight convert (fp32 -> bf16, fold softmax scale into Wq/bq) ----------------
__global__ __launch_bounds__(256) void convert_w(
    const float* __restrict__ Wq, const float* __restrict__ Wk,
    const float* __restrict__ Wv, const float* __restrict__ Wo,
    const float* __restrict__ bq, const float* __restrict__ bk,
    const float* __restrict__ bv, const float* __restrict__ bo,
    unsigned short* __restrict__ W4, float* __restrict__ b4) {
  int i = blockIdx.x * 256 + threadIdx.x;            // 4*512*512 total
  int p = i >> 18, idx = i & 262143;
  const float sc = 1.4426950408889634f * 0.04419417382415922f;  // log2(e) * 512^-0.5
  const float* W = (p == 0) ? Wq : (p == 1) ? Wk : (p == 2) ? Wv : Wo;
  float v = W[idx] * ((p == 0) ? sc : 1.0f);
  W4[i] = f2bf(v);
  if (idx < 512) {
    const float* bb = (p == 0) ? bq : (p == 1) ? bk : (p == 2) ? bv : bo;
    b4[(p << 9) + idx] = bb[idx] * ((p == 0) ? sc : 1.0f);
  }
}

// ---------------- transpose q (vectorized): fp32 [b][c][s] -> bf16 qT [b][s][c] ----------------
__global__ __launch_bounds__(256) void transpose_q(
    const float* __restrict__ q, unsigned short* __restrict__ qT) {
  __shared__ float tile[64][65];
  const int b = blockIdx.z, c0 = blockIdx.y * 64, s0 = blockIdx.x * 64;
  const int t = threadIdx.x;
  const int lx = t & 15, ly = t >> 4;
  #pragma unroll
  for (int i = 0; i < 4; i++) {
    int c = ly + i * 16;
    f32x4 v = *(const f32x4*)&q[((size_t)b * CD + c0 + c) * SEQ + s0 + lx * 4];
    tile[c][lx * 4 + 0] = v[0];
    tile[c][lx * 4 + 1] = v[1];
    tile[c][lx * 4 + 2] = v[2];
    tile[c][lx * 4 + 3] = v[3];
  }
  __syncthreads();
  #pragma unroll
  for (int i = 0; i < 4; i++) {
    int s = ly + i * 16;
    ushort4 o;
    o.x = f2bf(tile[lx * 4 + 0][s]);
    o.y = f2bf(tile[lx * 4 + 1][s]);
    o.z = f2bf(tile[lx * 4 + 2][s]);
    o.w = f2bf(tile[lx * 4 + 3][s]);
    *(ushort4*)&qT[((size_t)b * SEQ + s0 + s) * CD + c0 + lx * 4] = o;
  }
}

// ---------------- generalized BT-GEMM core: 128x128 tile, BK=64, 4 waves ----------------
__device__ __forceinline__ void gemm_core2(
    const unsigned short* __restrict__ Ap, size_t lda,
    const unsigned short* __restrict__ Bp, size_t ldb, int kmax,
    unsigned short* As, unsigned short* Bs, f32x4 acc[4][4]) {
  const int t = threadIdx.x;
  const int wid = t >> 6, lane = t & 63;
  const int l15 = lane & 15, l4 = lane >> 4;
  const int wr = wid >> 1, wc = wid & 1;
  for (int k0 = 0; k0 < kmax; k0 += 64) {
    #pragma unroll
    for (int j = 0; j < 4; j++) {
      int slot = j * 256 + t;
      int row = slot >> 3, kc = slot & 7;
      int kcs = kc ^ (row & 7);
      gload_lds16(Ap + (size_t)row * lda + k0 + kcs * 8, As + (j * 256 + wid * 64) * 8);
      gload_lds16(Bp + (size_t)row * ldb + k0 + kcs * 8, Bs + (j * 256 + wid * 64) * 8);
    }
    __syncthreads();
    #pragma unroll
    for (int ks = 0; ks < 2; ks++) {
      bf16x8 af[4], bf[4];
      #pragma unroll
      for (int i = 0; i < 4; i++) {
        int ra = wr * 64 + i * 16 + l15;
        af[i] = *(const bf16x8*)(As + ra * 64 + (((ks << 2) | l4) ^ (ra & 7)) * 8);
        int rb = wc * 64 + i * 16 + l15;
        bf[i] = *(const bf16x8*)(Bs + rb * 64 + (((ks << 2) | l4) ^ (rb & 7)) * 8);
      }
      #pragma unroll
      for (int i = 0; i < 4; i++)
        #pragma unroll
        for (int j = 0; j < 4; j++)
          acc[i][j] = MFMA16(af[i], bf[j], acc[i][j]);
    }
    __syncthreads();
  }
}

__device__ __forceinline__ void gemm_core(
    const unsigned short* __restrict__ Ap, const unsigned short* __restrict__ Bp,
    unsigned short* As, unsigned short* Bs, f32x4 acc[4][4]) {
  gemm_core2(Ap, 512, Bp, 512, 512, As, Bs, acc);
}

// ---------------- QKV projection, 256x256 4-phase; V stored fp8 (bf16 only if VfT) ------
__global__ __launch_bounds__(512, 2) void gemm_proj256(
    const unsigned short* __restrict__ qT, const unsigned short* __restrict__ W4,
    const float* __restrict__ b4,
    unsigned short* __restrict__ Qf, unsigned short* __restrict__ Kf,
    unsigned short* __restrict__ VfT, unsigned char* __restrict__ Vf8) {
  __shared__ unsigned short As[2][2][128 * 64];   // 64 KB
  __shared__ unsigned short Bs[2][2][128 * 64];   // 64 KB

  const int tid = threadIdx.x;
  const int wid = tid >> 6, lane = tid & 63;
  const int l15 = lane & 15, l4 = lane >> 4;
  const int wm = wid >> 2, wn = wid & 3;

  const int id = blockIdx.x;
  const int xcd = id & 7;
  const int w = id >> 3;                 // 0..47
  const int p = w >> 4;                  // 0..2
  const int sub = w & 15;
  const int mt = (xcd << 3) | (sub >> 1);  // 0..63
  const int nt = sub & 1;
  const int m0 = mt * 256;
  const int n0 = nt * 256;

  const unsigned short* Ap = qT + (size_t)m0 * 512;
  const unsigned short* Bp = W4 + ((size_t)p * 512 + n0) * 512;

#define PJ_HALF(DST, SRC, HALF, K0)                                           \
  _Pragma("unroll")                                                           \
  for (int i_ = 0; i_ < 2; i_++) {                                            \
    int sg = i_ * 512 + tid;                                                  \
    int row = sg >> 3, kc = sg & 7;                                           \
    int kcs = kc ^ (row & 7);                                                 \
    gload_lds16(SRC + (size_t)((HALF) * 128 + row) * 512 + (K0) + kcs * 8,    \
                &DST[sg * 8]);                                                \
  }

  f32x4 acc[8][4];
  #pragma unroll
  for (int i = 0; i < 8; i++)
    #pragma unroll
    for (int j = 0; j < 4; j++) acc[i][j] = (f32x4){0.f, 0.f, 0.f, 0.f};

  PJ_HALF(As[0][0], Ap, 0, 0)
  PJ_HALF(As[0][1], Ap, 1, 0)
  PJ_HALF(Bs[0][0], Bp, 0, 0)
  PJ_HALF(Bs[0][1], Bp, 1, 0)
  VM0;
  __builtin_amdgcn_s_barrier();

  bf16x8 afr[4][2], bfr0[2][2], bfr1[2][2];
  const int bh = wn >> 1;
  const int brow = (wn & 1) * 64;

  for (int t = 0; t < 8; t++) {
    const int d = t & 1;
    const unsigned short* Ah = As[d][wm];
    const unsigned short* Bh = Bs[d][bh];
    const int k0n = (t + 1) * 64;
    const bool more = (t < 7);

    // phase 0: read af-lo + bf-lo; stage A halves of t+1
    #pragma unroll
    for (int i = 0; i < 4; i++) {
      int r = i * 16 + l15;
      afr[i][0] = *(const bf16x8*)(Ah + r * 64 + ((l4) ^ (r & 7)) * 8);
      afr[i][1] = *(const bf16x8*)(Ah + r * 64 + ((4 | l4) ^ (r & 7)) * 8);
    }
    #pragma unroll
    for (int j = 0; j < 2; j++) {
      int r = brow + j * 16 + l15;
      bfr0[j][0] = *(const bf16x8*)(Bh + r * 64 + ((l4) ^ (r & 7)) * 8);
      bfr0[j][1] = *(const bf16x8*)(Bh + r * 64 + ((4 | l4) ^ (r & 7)) * 8);
    }
    if (more) {
      PJ_HALF(As[d ^ 1][0], Ap, 0, k0n)
      PJ_HALF(As[d ^ 1][1], Ap, 1, k0n)
    }
    __builtin_amdgcn_s_barrier();
    LGKM0;
    __builtin_amdgcn_s_setprio(1);
    #pragma unroll
    for (int ks = 0; ks < 2; ks++)
      #pragma unroll
      for (int i = 0; i < 4; i++)
        #pragma unroll
        for (int j = 0; j < 2; j++)
          acc[i][j] = MFMA16(afr[i][ks], bfr0[j][ks], acc[i][j]);
    __builtin_amdgcn_s_setprio(0);
    __builtin_amdgcn_s_barrier();

    // phase 1: read bf-hi; stage B halves of t+1
    #pragma unroll
    for (int j = 0; j < 2; j++) {
      int r = brow + (j + 2) * 16 + l15;
      bfr1[j][0] = *(const bf16x8*)(Bh + r * 64 + ((l4) ^ (r & 7)) * 8);
      bfr1[j][1] = *(const bf16x8*)(Bh + r * 64 + ((4 | l4) ^ (r & 7)) * 8);
    }
    if (more) {
      PJ_HALF(Bs[d ^ 1][0], Bp, 0, k0n)
      PJ_HALF(Bs[d ^ 1][1], Bp, 1, k0n)
    }
    __builtin_amdgcn_s_barrier();
    LGKM0;
    __builtin_amdgcn_s_setprio(1);
    #pragma unroll
    for (int ks = 0; ks < 2; ks++)
      #pragma unroll
      for (int i = 0; i < 4; i++)
        #pragma unroll
        for (int j = 0; j < 2; j++)
          acc[i][j + 2] = MFMA16(afr[i][ks], bfr1[j][ks], acc[i][j + 2]);
    __builtin_amdgcn_s_setprio(0);
    __builtin_amdgcn_s_barrier();

    // phase 2: read af-hi
    #pragma unroll
    for (int i = 0; i < 4; i++) {
      int r = 64 + i * 16 + l15;
      afr[i][0] = *(const bf16x8*)(Ah + r * 64 + ((l4) ^ (r & 7)) * 8);
      afr[i][1] = *(const bf16x8*)(Ah + r * 64 + ((4 | l4) ^ (r & 7)) * 8);
    }
    __builtin_amdgcn_s_barrier();
    LGKM0;
    __builtin_amdgcn_s_setprio(1);
    #pragma unroll
    for (int ks = 0; ks < 2; ks++)
      #pragma unroll
      for (int i = 0; i < 4; i++)
        #pragma unroll
        for (int j = 0; j < 2; j++)
          acc[i + 4][j + 2] = MFMA16(afr[i][ks], bfr1[j][ks], acc[i + 4][j + 2]);
    __builtin_amdgcn_s_setprio(0);
    __builtin_amdgcn_s_barrier();

    // phase 3: no reads; drain stages; flip
    __builtin_amdgcn_s_barrier();
    __builtin_amdgcn_s_setprio(1);
    #pragma unroll
    for (int ks = 0; ks < 2; ks++)
      #pragma unroll
      for (int i = 0; i < 4; i++)
        #pragma unroll
        for (int j = 0; j < 2; j++)
          acc[i + 4][j] = MFMA16(afr[i][ks], bfr0[j][ks], acc[i + 4][j]);
    __builtin_amdgcn_s_setprio(0);
    VM0;
    __builtin_amdgcn_s_barrier();
  }
#undef PJ_HALF

  // ---- epilogue: bias add; Q/K row-major store, V transposed store (fp8 / bf16) ----
  if (p < 2) {
    unsigned short* out = (p == 0) ? Qf : Kf;
    #pragma unroll
    for (int i = 0; i < 8; i++) {
      int m = m0 + wm * 128 + i * 16 + l4 * 4;
      #pragma unroll
      for (int j = 0; j < 4; j++) {
        int n = n0 + wn * 64 + j * 16 + l15;
        float bias = b4[p * 512 + n];
        #pragma unroll
        for (int r = 0; r < 4; r++)
          out[(size_t)(m + r) * 512 + n] = f2bf(acc[i][j][r] + bias);
      }
    }
  } else {
    #pragma unroll
    for (int i = 0; i < 8; i++) {
      int m = m0 + wm * 128 + i * 16 + l4 * 4;
      int bb = m >> 12, sb = m & 4095;
      #pragma unroll
      for (int j = 0; j < 4; j++) {
        int n = n0 + wn * 64 + j * 16 + l15;
        float bias = b4[2 * 512 + n];
        float v0 = acc[i][j][0] + bias, v1 = acc[i][j][1] + bias;
        float v2 = acc[i][j][2] + bias, v3 = acc[i][j][3] + bias;
        if (VfT) {
          ushort4 v;
          v.x = f2bf(v0); v.y = f2bf(v1); v.z = f2bf(v2); v.w = f2bf(v3);
          *(ushort4*)&VfT[((size_t)bb * CD + n) * SEQ + sb] = v;
        }
        if (Vf8)
          *(int*)&Vf8[((size_t)bb * CD + n) * SEQ + sb] = pk4_fp8(v0, v1, v2, v3);
      }
    }
  }
}

// ---------------- QK^T 256x256 tile, BK=64, SINGLE-buffer LDS (64KB -> 2 blocks/CU) -----
// Inter-block overlap covers stage/barrier stalls (m97/m114 mechanism). Per K-tile:
// {stage 8 gloads -> syncthreads -> 4 quadrant read+MFMA clusters -> syncthreads}.
__global__ __launch_bounds__(512, 2) void gemm_qk256(
    const unsigned short* __restrict__ Qf, const unsigned short* __restrict__ Kf,
    unsigned char* __restrict__ P8, float* __restrict__ partials,
    int bbase, int nbat) {
  __shared__ unsigned short As[2][128 * 64];   // 32 KB (two row-halves)
  __shared__ unsigned short Bs[2][128 * 64];   // 32 KB
  __shared__ float ssum[2][4][4][16];          // [wm][wn][j][l15]

  const int tid = threadIdx.x;
  const int wid = tid >> 6, lane = tid & 63;
  const int l15 = lane & 15, l4 = lane >> 4;
  const int wm = wid >> 2, wn = wid & 3;

  const int id = blockIdx.x;
  const int xcd = id & 7;
  int z, qt, kt;
  if (nbat == 4) {
    z = xcd >> 1;
    int w = id >> 3;                     // 0..127
    qt = ((xcd & 1) << 3) | (w >> 4);    // 16 q-tiles
    kt = w & 15;
  } else {
    z = 0;
    int w = id >> 3;                     // 0..31
    qt = (xcd << 1) | (w >> 4);
    kt = w & 15;
  }
  const int b = bbase + z;
  const int m0 = kt * 256;               // k rows
  const int n0 = qt * 256;               // q rows

  const unsigned short* Ap = Kf + ((size_t)b * SEQ + m0) * CD;
  const unsigned short* Bp = Qf + ((size_t)b * SEQ + n0) * CD;

#define QK_HALF(DST, SRC, HALF, K0)                                           \
  _Pragma("unroll")                                                           \
  for (int i_ = 0; i_ < 2; i_++) {                                            \
    int sg = i_ * 512 + tid;                                                  \
    int row = sg >> 3, kc = sg & 7;                                           \
    int kcs = kc ^ (row & 7);                                                 \
    gload_lds16(SRC + (size_t)((HALF) * 128 + row) * CD + (K0) + kcs * 8,     \
                &DST[sg * 8]);                                                \
  }

  f32x4 acc[8][4];
  #pragma unroll
  for (int i = 0; i < 8; i++)
    #pragma unroll
    for (int j = 0; j < 4; j++) acc[i][j] = (f32x4){0.f, 0.f, 0.f, 0.f};

  bf16x8 afr[4][2], bfr0[2][2], bfr1[2][2];
  const int bh = wn >> 1;
  const int brow = (wn & 1) * 64;

  for (int t = 0; t < 8; t++) {
    const int k0 = t * 64;
    // ---- stage tile t (single buffer) ----
    QK_HALF(As[0], Ap, 0, k0)
    QK_HALF(As[1], Ap, 1, k0)
    QK_HALF(Bs[0], Bp, 0, k0)
    QK_HALF(Bs[1], Bp, 1, k0)
    __syncthreads();                    // drains vmcnt; tile visible

    const unsigned short* Ah = As[wm];
    const unsigned short* Bh = Bs[bh];

    // quadrant 0: af-lo x bf-lo
    #pragma unroll
    for (int i = 0; i < 4; i++) {
      int r = i * 16 + l15;
      afr[i][0] = *(const bf16x8*)(Ah + r * 64 + ((l4) ^ (r & 7)) * 8);
      afr[i][1] = *(const bf16x8*)(Ah + r * 64 + ((4 | l4) ^ (r & 7)) * 8);
    }
    #pragma unroll
    for (int j = 0; j < 2; j++) {
      int r = brow + j * 16 + l15;
      bfr0[j][0] = *(const bf16x8*)(Bh + r * 64 + ((l4) ^ (r & 7)) * 8);
      bfr0[j][1] = *(const bf16x8*)(Bh + r * 64 + ((4 | l4) ^ (r & 7)) * 8);
    }
    __builtin_amdgcn_s_setprio(1);
    #pragma unroll
    for (int ks = 0; ks < 2; ks++)
      #pragma unroll
      for (int i = 0; i < 4; i++)
        #pragma unroll
        for (int j = 0; j < 2; j++)
          acc[i][j] = MFMA16(afr[i][ks], bfr0[j][ks], acc[i][j]);
    __builtin_amdgcn_s_setprio(0);

    // quadrant 1: af-lo x bf-hi
    #pragma unroll
    for (int j = 0; j < 2; j++) {
      int r = brow + (j + 2) * 16 + l15;
      bfr1[j][0] = *(const bf16x8*)(Bh + r * 64 + ((l4) ^ (r & 7)) * 8);
      bfr1[j][1] = *(const bf16x8*)(Bh + r * 64 + ((4 | l4) ^ (r & 7)) * 8);
    }
    __builtin_amdgcn_s_setprio(1);
    #pragma unroll
    for (int ks = 0; ks < 2; ks++)
      #pragma unroll
      for (int i = 0; i < 4; i++)
        #pragma unroll
        for (int j = 0; j < 2; j++)
          acc[i][j + 2] = MFMA16(afr[i][ks], bfr1[j][ks], acc[i][j + 2]);
    __builtin_amdgcn_s_setprio(0);

    // quadrant 2: af-hi x bf-hi
    #pragma unroll
    for (int i = 0; i < 4; i++) {
      int r = 64 + i * 16 + l15;
      afr[i][0] = *(const bf16x8*)(Ah + r * 64 + ((l4) ^ (r & 7)) * 8);
      afr[i][1] = *(const bf16x8*)(Ah + r * 64 + ((4 | l4) ^ (r & 7)) * 8);
    }
    __builtin_amdgcn_s_setprio(1);
    #pragma unroll
    for (int ks = 0; ks < 2; ks++)
      #pragma unroll
      for (int i = 0; i < 4; i++)
        #pragma unroll
        for (int j = 0; j < 2; j++)
          acc[i + 4][j + 2] = MFMA16(afr[i][ks], bfr1[j][ks], acc[i + 4][j + 2]);

    // quadrant 3: af-hi x bf-lo
    #pragma unroll
    for (int ks = 0; ks < 2; ks++)
      #pragma unroll
      for (int i = 0; i < 4; i++)
        #pragma unroll
        for (int j = 0; j < 2; j++)
          acc[i + 4][j] = MFMA16(afr[i][ks], bfr0[j][ks], acc[i + 4][j]);
    __builtin_amdgcn_s_setprio(0);

    __syncthreads();                    // all reads done before next stage
  }
#undef QK_HALF

  // ---- epilogue: exp2, store P fp8 (4B), row partial sums ----
  unsigned char* Pz = P8 + (size_t)z * SEQ * SEQ;
  float sj[4] = {0.f, 0.f, 0.f, 0.f};
  #pragma unroll
  for (int i = 0; i < 8; i++) {
    int m = m0 + wm * 128 + i * 16 + l4 * 4;      // k (4 consecutive)
    #pragma unroll
    for (int j = 0; j < 4; j++) {
      int n = n0 + wn * 64 + j * 16 + l15;        // q
      float p0 = __builtin_amdgcn_exp2f(acc[i][j][0]);
      float p1 = __builtin_amdgcn_exp2f(acc[i][j][1]);
      float p2 = __builtin_amdgcn_exp2f(acc[i][j][2]);
      float p3 = __builtin_amdgcn_exp2f(acc[i][j][3]);
      sj[j] += (p0 + p1) + (p2 + p3);
      *(int*)&Pz[(size_t)n * SEQ + m] = pk4_fp8(p0, p1, p2, p3);
    }
  }
  #pragma unroll
  for (int j = 0; j < 4; j++) {
    float s = sj[j];
    s += __shfl_xor(s, 16, 64);
    s += __shfl_xor(s, 32, 64);
    if (lane < 16) ssum[wm][wn][j][l15] = s;
  }
  __syncthreads();
  if (tid < 256) {
    int wn_ = tid >> 6, j_ = (tid >> 4) & 3, l_ = tid & 15;
    float s = ssum[0][wn_][j_][l_] + ssum[1][wn_][j_][l_];
    partials[((size_t)z * SEQ + n0 + tid) * 16 + kt] = s;
  }
}

// ---------------- l reduce: linv[q] = 1 / sum_16 partials[q][.] ----------------
__global__ __launch_bounds__(256) void reduce_l(
    const float* __restrict__ partials, float* __restrict__ linv) {
  int i = blockIdx.x * 256 + threadIdx.x;
  const float* p = partials + (size_t)i * 16;
  float s = 0.f;
  #pragma unroll
  for (int j = 0; j < 16; j++) s += p[j];
  linv[i] = 1.0f / s;
}

// ---------------- PV fp8 GEMM: 128x64 tile, 4 waves, BK=128 fp8, 2-barrier ----------------
__global__ __launch_bounds__(256) void gemm_pv8(
    const unsigned char* __restrict__ Vf8, const unsigned char* __restrict__ P8,
    const float* __restrict__ linv, unsigned short* __restrict__ Ao,
    int bbase, int nbat) {
  __shared__ unsigned char As[128 * 128];   // 16 KB
  __shared__ unsigned char Bs[64 * 128];    // 8 KB
  const int tid = threadIdx.x;
  const int wid = tid >> 6, lane = tid & 63;
  const int l15 = lane & 15, l4 = lane >> 4;
  const int wr = wid >> 1, wc = wid & 1;

  const int id = blockIdx.x;
  const int xcd = id & 7;
  int z, qt, ct;
  if (nbat == 4) {
    z = xcd >> 1;
    int w = id >> 3;                      // 0..127
    qt = ((xcd & 1) << 5) | (w >> 2);     // 0..63
    ct = w & 3;
  } else {
    z = 0;
    int w = id >> 3;                      // 0..31
    qt = (xcd << 3) | (w >> 2);
    ct = w & 3;
  }
  const int b = bbase + z;
  const int n0 = qt * 64, m0 = ct * 128;

  const unsigned char* Ap = Vf8 + ((size_t)b * CD + m0) * SEQ;
  const unsigned char* Bp = P8 + (size_t)z * SEQ * SEQ + (size_t)n0 * SEQ;

  f32x4 acc[4][2];
  #pragma unroll
  for (int i = 0; i < 4; i++) {
    acc[i][0] = (f32x4){0.f, 0.f, 0.f, 0.f};
    acc[i][1] = (f32x4){0.f, 0.f, 0.f, 0.f};
  }

  for (int k0 = 0; k0 < SEQ; k0 += 128) {
    #pragma unroll
    for (int i = 0; i < 4; i++) {
      int sg = i * 256 + tid;
      int row = sg >> 3, kc = sg & 7;
      int kcs = kc ^ (row & 7);
      gload_lds16(Ap + (size_t)row * SEQ + k0 + kcs * 16, As + sg * 16);
    }
    #pragma unroll
    for (int i = 0; i < 2; i++) {
      int sg = i * 256 + tid;
      int row = sg >> 3, kc = sg & 7;
      int kcs = kc ^ (row & 7);
      gload_lds16(Bp + (size_t)row * SEQ + k0 + kcs * 16, Bs + sg * 16);
    }
    __syncthreads();
    #pragma unroll
    for (int ks = 0; ks < 4; ks++) {
      i64frag af[4], bf[2];
      const int ch = ks * 2 + (l4 >> 1);
      const int hb = (l4 & 1) * 8;
      #pragma unroll
      for (int i = 0; i < 4; i++) {
        int ra = wr * 64 + i * 16 + l15;
        af[i] = *(const i64frag*)(As + ra * 128 + (ch ^ (ra & 7)) * 16 + hb);
      }
      #pragma unroll
      for (int j = 0; j < 2; j++) {
        int rb = wc * 32 + j * 16 + l15;
        bf[j] = *(const i64frag*)(Bs + rb * 128 + (ch ^ (rb & 7)) * 16 + hb);
      }
      #pragma unroll
      for (int i = 0; i < 4; i++)
        #pragma unroll
        for (int j = 0; j < 2; j++)
          acc[i][j] = MFMA8(af[i], bf[j], acc[i][j]);
    }
    __syncthreads();
  }

  #pragma unroll
  for (int j = 0; j < 2; j++) {
    int n = n0 + wc * 32 + j * 16 + l15;        // q
    float inv = linv[(size_t)z * SEQ + n];
    #pragma unroll
    for (int i = 0; i < 4; i++) {
      int m = m0 + wr * 64 + i * 16 + l4 * 4;   // c
      ushort4 o4;
      o4.x = f2bf(acc[i][j][0] * inv);
      o4.y = f2bf(acc[i][j][1] * inv);
      o4.z = f2bf(acc[i][j][2] * inv);
      o4.w = f2bf(acc[i][j][3] * inv);
      *(ushort4*)&Ao[((size_t)b * SEQ + n) * CD + m] = o4;
    }
  }
}

// ---------------- flash attention v4 (fallback when workspace is small) ----------------
#define SECTION(T, VRC, VRP, DOPV)                                              \
  {                                                                             \
    const int t_ = (T);                                                         \
    const unsigned short* vt_ = vbase + t_ * 32;                                \
    _Pragma("unroll")                                                           \
    for (int i = 0; i < 8; i++)                                                 \
      VRC[i] = *(const bf16x8*)(vt_ + (size_t)i * 16 * SEQ);                    \
    f32x4 sf = (f32x4){0.f, 0.f, 0.f, 0.f};                                     \
    __builtin_amdgcn_s_setprio(1);                                              \
    {                                                                           \
      const char* krow = (const char*)(Ks + (size_t)(t_ & 3) * 16384) +         \
                         (s * 16 + l15) * 1024;                                 \
      const int kswz = (l15 & 7) << 4;                                          \
      _Pragma("unroll")                                                         \
      for (int ck = 0; ck < 16; ck++) {                                         \
        bf16x8 kf = *(const bf16x8*)(krow + ((ck * 64 + l4 * 16) ^ kswz));      \
        sf = MFMA16(kf, qreg[ck], sf);                                          \
      }                                                                         \
    }                                                                           \
    if (DOPV) {                                                                 \
      _Pragma("unroll")                                                         \
      for (int jf = 0; jf < 2; jf++) {                                          \
        int qv = qw * 32 + jf * 16 + l15;                                       \
        bf16x8 pb = *(const bf16x8*)((const char*)Ps + ((t_ + 1) & 1) * 4096 +  \
                                     qv * 64 +                                  \
                                     ((l4 * 16) ^ (((qv >> 1) & 3) << 4)));     \
        _Pragma("unroll")                                                       \
        for (int i = 0; i < 8; i++)                                             \
          acc[i][jf] = MFMA16(VRP[i], pb, acc[i][jf]);                          \
      }                                                                         \
    }                                                                           \
    __builtin_amdgcn_s_setprio(0);                                              \
    {                                                                           \
      float p0 = __builtin_amdgcn_exp2f(sf[0]);                                 \
      float p1 = __builtin_amdgcn_exp2f(sf[1]);                                 \
      float p2 = __builtin_amdgcn_exp2f(sf[2]);                                 \
      float p3 = __builtin_amdgcn_exp2f(sf[3]);                                 \
      l_acc[0] += p0; l_acc[1] += p1; l_acc[2] += p2; l_acc[3] += p3;           \
      ushort4 pk;                                                               \
      pk.x = f2bf(p0); pk.y = f2bf(p1); pk.z = f2bf(p2); pk.w = f2bf(p3);       \
      int q_ = g * 16 + l15;                                                    \
      int off = (t_ & 1) * 4096 + q_ * 64 +                                     \
                ((s * 32 + l4 * 8) ^ (((q_ >> 1) & 3) << 4));                   \
      *(ushort4*)((char*)Ps + off) = pk;                                        \
    }                                                                           \
    {                                                                           \
      int tt = (t_ + 2 < 128) ? t_ + 2 : 127;                                   \
      const unsigned short* kn = kbT + (size_t)tt * 32 * CD;                    \
      unsigned short* kdst = Ks + (size_t)((t_ + 2) & 3) * 16384;               \
      _Pragma("unroll")                                                         \
      for (int i = 0; i < 4; i++) {                                             \
        int slot = i * 512 + tid;                                               \
        int row = slot >> 6, kc = slot & 63;                                    \
        int kcs = kc ^ (row & 7);                                               \
        gload_lds16(kn + (size_t)row * CD + kcs * 8,                            \
                    kdst + (size_t)(i * 512 + wid * 64) * 8);                   \
      }                                                                         \
    }                                                                           \
    LGKM0;                                                                      \
    VMC12;                                                                      \
    __builtin_amdgcn_s_barrier();                                               \
  }

__global__ __launch_bounds__(512, 2) void flash_attn(
    const unsigned short* __restrict__ Qf, const unsigned short* __restrict__ Kf,
    const unsigned short* __restrict__ VfT, unsigned short* __restrict__ Ao) {
  __shared__ unsigned short Ks[4 * 32 * 512];
  __shared__ unsigned short Ps[2 * 64 * 32];
  __shared__ float ssum[4][2][16];

  const int tid = threadIdx.x;
  const int wid = tid >> 6, lane = tid & 63;
  const int l15 = lane & 15, l4 = lane >> 4;
  const int s = wid & 1, g = wid >> 1;
  const int cw = wid & 3, qw = wid >> 2;

  const int id = blockIdx.x;
  const int xcd = id & 7;
  const int b = xcd >> 1;
  const int q0 = ((id >> 3) + ((xcd & 1) << 5)) * 64;

  const unsigned short* kbT = Kf + (size_t)b * SEQ * CD;
  const unsigned short* vbase = VfT + ((size_t)b * CD + cw * 128 + l15) * SEQ + l4 * 8;

  #pragma unroll
  for (int tt = 0; tt < 2; tt++) {
    const unsigned short* kn = kbT + (size_t)tt * 32 * CD;
    unsigned short* kdst = Ks + (size_t)tt * 16384;
    #pragma unroll
    for (int i = 0; i < 4; i++) {
      int slot = i * 512 + tid;
      int row = slot >> 6, kc = slot & 63;
      int kcs = kc ^ (row & 7);
      gload_lds16(kn + (size_t)row * CD + kcs * 8, kdst + (size_t)(i * 512 + wid * 64) * 8);
    }
  }

  bf16x8 qreg[16];
  {
    const unsigned short* qp = Qf + ((size_t)b * SEQ + q0 + g * 16 + l15) * CD + l4 * 8;
    #pragma unroll
    for (int ck = 0; ck < 16; ck++) qreg[ck] = *(const bf16x8*)(qp + ck * 32);
  }

  f32x4 acc[8][2];
  #pragma unroll
  for (int i = 0; i < 8; i++) {
    acc[i][0] = (f32x4){0.f, 0.f, 0.f, 0.f};
    acc[i][1] = (f32x4){0.f, 0.f, 0.f, 0.f};
  }
  f32x4 l_acc = (f32x4){0.f, 0.f, 0.f, 0.f};

  bf16x8 vrA[8], vrB[8];

  VM0;
  __builtin_amdgcn_s_barrier();

  SECTION(0, vrA, vrB, 0);
  for (int t = 1; t < 127; t += 2) {
    SECTION(t, vrB, vrA, 1);
    SECTION(t + 1, vrA, vrB, 1);
  }
  SECTION(127, vrB, vrA, 1);

  #pragma unroll
  for (int jf = 0; jf < 2; jf++) {
    int qv = qw * 32 + jf * 16 + l15;
    bf16x8 pb = *(const bf16x8*)((const char*)Ps + 4096 + qv * 64 +
                                 ((l4 * 16) ^ (((qv >> 1) & 3) << 4)));
    #pragma unroll
    for (int i = 0; i < 8; i++)
      acc[i][jf] = MFMA16(vrB[i], pb, acc[i][jf]);
  }

  float strip = (l_acc[0] + l_acc[1]) + (l_acc[2] + l_acc[3]);
  strip += __shfl_xor(strip, 16, 64);
  strip += __shfl_xor(strip, 32, 64);
  __syncthreads();
  if (lane < 16) ssum[g][s][l15] = strip;
  __syncthreads();

  #pragma unroll
  for (int jf = 0; jf < 2; jf++) {
    int gq = qw * 2 + jf;
    float inv = 1.0f / (ssum[gq][0][l15] + ssum[gq][1][l15]);
    #pragma unroll
    for (int i = 0; i < 8; i++) {
      int c0 = cw * 128 + i * 16 + l4 * 4;
      ushort4 o4;
      o4.x = f2bf(acc[i][jf][0] * inv);
      o4.y = f2bf(acc[i][jf][1] * inv);
      o4.z = f2bf(acc[i][jf][2] * inv);
      o4.w = f2bf(acc[i][jf][3] * inv);
      *(ushort4*)&Ao[((size_t)b * SEQ + q0 + qw * 32 + jf * 16 + l15) * CD + c0] = o4;
    }
  }
}

// ---------------- output projection: out[b][o][s] fp32 ----------------
__global__ __launch_bounds__(256) void gemm_out(
    const unsigned short* __restrict__ W4, const float* __restrict__ b4,
    const unsigned short* __restrict__ Ao, float* __restrict__ out) {
  __shared__ unsigned short As[128 * 64], Bs[128 * 64];
  const int b = blockIdx.z;
  const int n0 = blockIdx.x * 128, m0 = blockIdx.y * 128;
  f32x4 acc[4][4];
  #pragma unroll
  for (int i = 0; i < 4; i++)
    #pragma unroll
    for (int j = 0; j < 4; j++) acc[i][j] = (f32x4){0.f, 0.f, 0.f, 0.f};
  gemm_core(W4 + ((size_t)3 * 512 + m0) * 512, Ao + ((size_t)b * SEQ + n0) * 512, As, Bs, acc);

  const int t = threadIdx.x;
  const int wid = t >> 6, lane = t & 63;
  const int l15 = lane & 15, l4 = lane >> 4;
  const int wr = wid >> 1, wc = wid & 1;
  #pragma unroll
  for (int i = 0; i < 4; i++) {
    int m = m0 + wr * 64 + i * 16 + l4 * 4;
    #pragma unroll
    for (int j = 0; j < 4; j++) {
      int n = n0 + wc * 64 + j * 16 + l15;
      #pragma unroll
      for (int r = 0; r < 4; r++)
        out[((size_t)b * CD + m + r) * SEQ + n] = acc[i][j][r] + b4[3 * 512 + m + r];
    }
  }
}

extern "C" void kernel_launch(void* const* d_in, const int* in_sizes, int n_in,
                              void* d_out, int out_size, void* d_ws, size_t ws_size,
                              hipStream_t stream) {
  (void)in_sizes; (void)n_in; (void)out_size;
  const float* q  = (const float*)d_in[0];
  const float* Wq = (const float*)d_in[1];
  const float* bq = (const float*)d_in[2];
  const float* Wk = (const float*)d_in[3];
  const float* bk = (const float*)d_in[4];
  const float* Wv = (const float*)d_in[5];
  const float* bv = (const float*)d_in[6];
  const float* Wo = (const float*)d_in[7];
  const float* bo = (const float*)d_in[8];
  float* out = (float*)d_out;

  char* ws = (char*)d_ws;
  const size_t MB = (size_t)1 << 20;
  unsigned short* qT  = (unsigned short*)(ws);            // 16MB (reused as Ao)
  unsigned short* Qf  = (unsigned short*)(ws + 16 * MB);
  unsigned short* Kf  = (unsigned short*)(ws + 32 * MB);
  unsigned short* VfT = (unsigned short*)(ws + 48 * MB);  // bf16 V (flash fallback only)
  unsigned short* Ao = qT;

  if (ws_size >= 134 * MB) {
    // fp8 path, all 4 batches: P8 overlays VfT region (dead on this path)
    unsigned char* P8    = (unsigned char*)(ws + 48 * MB);   // 64MB -> 48..112
    unsigned short* W4   = (unsigned short*)(ws + 112 * MB); // 2MB
    float* b4            = (float*)(ws + 114 * MB);          // 8KB
    unsigned char* Vf8   = (unsigned char*)(ws + 115 * MB);  // 8MB
    float* partials      = (float*)(ws + 123 * MB);          // 1MB
    float* linv          = (float*)(ws + 124 * MB + 512 * 1024);

    convert_w<<<4096, 256, 0, stream>>>(Wq, Wk, Wv, Wo, bq, bk, bv, bo, W4, b4);
    transpose_q<<<dim3(64, 8, 4), 256, 0, stream>>>(q, qT);
    gemm_proj256<<<384, 512, 0, stream>>>(qT, W4, b4, Qf, Kf, (unsigned short*)nullptr, Vf8);
    gemm_qk256<<<1024, 512, 0, stream>>>(Qf, Kf, P8, partials, 0, 4);
    reduce_l<<<64, 256, 0, stream>>>(partials, linv);
    gemm_pv8<<<1024, 256, 0, stream>>>(Vf8, P8, linv, Ao, 0, 4);
    gemm_out<<<dim3(32, 4, 4), 256, 0, stream>>>(W4, b4, Ao, out);
  } else if (ws_size >= 101 * MB) {
    // fp8 path, per-batch: P8 (16MB) overlays VfT region
    unsigned char* P8    = (unsigned char*)(ws + 48 * MB);   // 16MB -> 48..64
    unsigned short* W4   = (unsigned short*)(ws + 64 * MB);  // 2MB
    float* b4            = (float*)(ws + 66 * MB);           // 8KB
    unsigned char* Vf8   = (unsigned char*)(ws + 67 * MB);   // 8MB -> 67..75
    float* partials      = (float*)(ws + 75 * MB);           // 256KB
    float* linv          = (float*)(ws + 76 * MB);           // 16KB

    convert_w<<<4096, 256, 0, stream>>>(Wq, Wk, Wv, Wo, bq, bk, bv, bo, W4, b4);
    transpose_q<<<dim3(64, 8, 4), 256, 0, stream>>>(q, qT);
    gemm_proj256<<<384, 512, 0, stream>>>(qT, W4, b4, Qf, Kf, (unsigned short*)nullptr, Vf8);
    for (int bb = 0; bb < 4; ++bb) {
      gemm_qk256<<<256, 512, 0, stream>>>(Qf, Kf, P8, partials, bb, 1);
      reduce_l<<<16, 256, 0, stream>>>(partials, linv);
      gemm_pv8<<<256, 256, 0, stream>>>(Vf8, P8, linv, Ao, bb, 1);
    }
    gemm_out<<<dim3(32, 4, 4), 256, 0, stream>>>(W4, b4, Ao, out);
  } else {
    // bf16 flash fallback
    unsigned short* W4 = (unsigned short*)(ws + 64 * MB);
    float* b4          = (float*)(ws + 66 * MB);
    convert_w<<<4096, 256, 0, stream>>>(Wq, Wk, Wv, Wo, bq, bk, bv, bo, W4, b4);
    transpose_q<<<dim3(64, 8, 4), 256, 0, stream>>>(q, qT);
    gemm_proj256<<<384, 512, 0, stream>>>(qT, W4, b4, Qf, Kf, VfT, (unsigned char*)nullptr);
    flash_attn<<<256, 512, 0, stream>>>(Qf, Kf, VfT, Ao);
    gemm_out<<<dim3(32, 4, 4), 256, 0, stream>>>(W4, b4, Ao, out);
  }
}

// Round 22
// 228.725 us; speedup vs baseline: 1.0253x; 1.0253x over previous
//
#include <hip/hip_runtime.h>

typedef short bf16x8 __attribute__((ext_vector_type(8)));
typedef float f32x4 __attribute__((ext_vector_type(4)));
typedef long i64frag;

#define MFMA16(a, b, c) __builtin_amdgcn_mfma_f32_16x16x32_bf16((a), (b), (c), 0, 0, 0)
#define MFMA8(a, b, c) __builtin_amdgcn_mfma_f32_16x16x32_fp8_fp8((a), (b), (c), 0, 0, 0)

#define SEQ 4096
#define CD 512

#define LGKM0 asm volatile("s_waitcnt lgkmcnt(0)" ::: "memory")
#define VM0   asm volatile("s_waitcnt vmcnt(0)" ::: "memory")
#define VMC12 asm volatile("s_waitcnt vmcnt(12)" ::: "memory")

__device__ __forceinline__ unsigned short f2bf(float f) {
  unsigned u = __builtin_bit_cast(unsigned, f);
  u = u + 0x7FFFu + ((u >> 16) & 1u);
  return (unsigned short)(u >> 16);
}

// pack 4 floats -> 4 OCP e4m3 bytes (gfx950 HW cvt)
__device__ __forceinline__ int pk4_fp8(float p0, float p1, float p2, float p3) {
  int w = __builtin_amdgcn_cvt_pk_fp8_f32(p0, p1, 0, false);
  w = __builtin_amdgcn_cvt_pk_fp8_f32(p2, p3, w, true);
  return w;
}

__device__ __forceinline__ void gload_lds16(const void* g, void* l) {
  __builtin_amdgcn_global_load_lds(
      (const __attribute__((address_space(1))) void*)g,
      (__attribute__((address_space(3))) void*)l, 16, 0, 0);
}

// ---------------- weight convert (fp32 -> bf16, fold softmax scale into Wq/bq) ----------------
__global__ __launch_bounds__(256) void convert_w(
    const float* __restrict__ Wq, const float* __restrict__ Wk,
    const float* __restrict__ Wv, const float* __restrict__ Wo,
    const float* __restrict__ bq, const float* __restrict__ bk,
    const float* __restrict__ bv, const float* __restrict__ bo,
    unsigned short* __restrict__ W4, float* __restrict__ b4) {
  int i = blockIdx.x * 256 + threadIdx.x;            // 4*512*512 total
  int p = i >> 18, idx = i & 262143;
  const float sc = 1.4426950408889634f * 0.04419417382415922f;  // log2(e) * 512^-0.5
  const float* W = (p == 0) ? Wq : (p == 1) ? Wk : (p == 2) ? Wv : Wo;
  float v = W[idx] * ((p == 0) ? sc : 1.0f);
  W4[i] = f2bf(v);
  if (idx < 512) {
    const float* bb = (p == 0) ? bq : (p == 1) ? bk : (p == 2) ? bv : bo;
    b4[(p << 9) + idx] = bb[idx] * ((p == 0) ? sc : 1.0f);
  }
}

// ---------------- transpose q (vectorized): fp32 [b][c][s] -> bf16 qT [b][s][c] ----------------
__global__ __launch_bounds__(256) void transpose_q(
    const float* __restrict__ q, unsigned short* __restrict__ qT) {
  __shared__ float tile[64][65];
  const int b = blockIdx.z, c0 = blockIdx.y * 64, s0 = blockIdx.x * 64;
  const int t = threadIdx.x;
  const int lx = t & 15, ly = t >> 4;
  #pragma unroll
  for (int i = 0; i < 4; i++) {
    int c = ly + i * 16;
    f32x4 v = *(const f32x4*)&q[((size_t)b * CD + c0 + c) * SEQ + s0 + lx * 4];
    tile[c][lx * 4 + 0] = v[0];
    tile[c][lx * 4 + 1] = v[1];
    tile[c][lx * 4 + 2] = v[2];
    tile[c][lx * 4 + 3] = v[3];
  }
  __syncthreads();
  #pragma unroll
  for (int i = 0; i < 4; i++) {
    int s = ly + i * 16;
    ushort4 o;
    o.x = f2bf(tile[lx * 4 + 0][s]);
    o.y = f2bf(tile[lx * 4 + 1][s]);
    o.z = f2bf(tile[lx * 4 + 2][s]);
    o.w = f2bf(tile[lx * 4 + 3][s]);
    *(ushort4*)&qT[((size_t)b * SEQ + s0 + s) * CD + c0 + lx * 4] = o;
  }
}

// ---------------- generalized BT-GEMM core: 128x128 tile, BK=64, 4 waves ----------------
__device__ __forceinline__ void gemm_core2(
    const unsigned short* __restrict__ Ap, size_t lda,
    const unsigned short* __restrict__ Bp, size_t ldb, int kmax,
    unsigned short* As, unsigned short* Bs, f32x4 acc[4][4]) {
  const int t = threadIdx.x;
  const int wid = t >> 6, lane = t & 63;
  const int l15 = lane & 15, l4 = lane >> 4;
  const int wr = wid >> 1, wc = wid & 1;
  for (int k0 = 0; k0 < kmax; k0 += 64) {
    #pragma unroll
    for (int j = 0; j < 4; j++) {
      int slot = j * 256 + t;
      int row = slot >> 3, kc = slot & 7;
      int kcs = kc ^ (row & 7);
      gload_lds16(Ap + (size_t)row * lda + k0 + kcs * 8, As + (j * 256 + wid * 64) * 8);
      gload_lds16(Bp + (size_t)row * ldb + k0 + kcs * 8, Bs + (j * 256 + wid * 64) * 8);
    }
    __syncthreads();
    #pragma unroll
    for (int ks = 0; ks < 2; ks++) {
      bf16x8 af[4], bf[4];
      #pragma unroll
      for (int i = 0; i < 4; i++) {
        int ra = wr * 64 + i * 16 + l15;
        af[i] = *(const bf16x8*)(As + ra * 64 + (((ks << 2) | l4) ^ (ra & 7)) * 8);
        int rb = wc * 64 + i * 16 + l15;
        bf[i] = *(const bf16x8*)(Bs + rb * 64 + (((ks << 2) | l4) ^ (rb & 7)) * 8);
      }
      #pragma unroll
      for (int i = 0; i < 4; i++)
        #pragma unroll
        for (int j = 0; j < 4; j++)
          acc[i][j] = MFMA16(af[i], bf[j], acc[i][j]);
    }
    __syncthreads();
  }
}

__device__ __forceinline__ void gemm_core(
    const unsigned short* __restrict__ Ap, const unsigned short* __restrict__ Bp,
    unsigned short* As, unsigned short* Bs, f32x4 acc[4][4]) {
  gemm_core2(Ap, 512, Bp, 512, 512, As, Bs, acc);
}

// ---------------- QKV projection, 256x256 4-phase; V stored fp8 (bf16 only if VfT) ------
__global__ __launch_bounds__(512, 2) void gemm_proj256(
    const unsigned short* __restrict__ qT, const unsigned short* __restrict__ W4,
    const float* __restrict__ b4,
    unsigned short* __restrict__ Qf, unsigned short* __restrict__ Kf,
    unsigned short* __restrict__ VfT, unsigned char* __restrict__ Vf8) {
  __shared__ unsigned short As[2][2][128 * 64];   // 64 KB
  __shared__ unsigned short Bs[2][2][128 * 64];   // 64 KB

  const int tid = threadIdx.x;
  const int wid = tid >> 6, lane = tid & 63;
  const int l15 = lane & 15, l4 = lane >> 4;
  const int wm = wid >> 2, wn = wid & 3;

  const int id = blockIdx.x;
  const int xcd = id & 7;
  const int w = id >> 3;                 // 0..47
  const int p = w >> 4;                  // 0..2
  const int sub = w & 15;
  const int mt = (xcd << 3) | (sub >> 1);  // 0..63
  const int nt = sub & 1;
  const int m0 = mt * 256;
  const int n0 = nt * 256;

  const unsigned short* Ap = qT + (size_t)m0 * 512;
  const unsigned short* Bp = W4 + ((size_t)p * 512 + n0) * 512;

#define PJ_HALF(DST, SRC, HALF, K0)                                           \
  _Pragma("unroll")                                                           \
  for (int i_ = 0; i_ < 2; i_++) {                                            \
    int sg = i_ * 512 + tid;                                                  \
    int row = sg >> 3, kc = sg & 7;                                           \
    int kcs = kc ^ (row & 7);                                                 \
    gload_lds16(SRC + (size_t)((HALF) * 128 + row) * 512 + (K0) + kcs * 8,    \
                &DST[sg * 8]);                                                \
  }

  f32x4 acc[8][4];
  #pragma unroll
  for (int i = 0; i < 8; i++)
    #pragma unroll
    for (int j = 0; j < 4; j++) acc[i][j] = (f32x4){0.f, 0.f, 0.f, 0.f};

  PJ_HALF(As[0][0], Ap, 0, 0)
  PJ_HALF(As[0][1], Ap, 1, 0)
  PJ_HALF(Bs[0][0], Bp, 0, 0)
  PJ_HALF(Bs[0][1], Bp, 1, 0)
  VM0;
  __builtin_amdgcn_s_barrier();

  bf16x8 afr[4][2], bfr0[2][2], bfr1[2][2];
  const int bh = wn >> 1;
  const int brow = (wn & 1) * 64;

  for (int t = 0; t < 8; t++) {
    const int d = t & 1;
    const unsigned short* Ah = As[d][wm];
    const unsigned short* Bh = Bs[d][bh];
    const int k0n = (t + 1) * 64;
    const bool more = (t < 7);

    // phase 0: read af-lo + bf-lo; stage A halves of t+1
    #pragma unroll
    for (int i = 0; i < 4; i++) {
      int r = i * 16 + l15;
      afr[i][0] = *(const bf16x8*)(Ah + r * 64 + ((l4) ^ (r & 7)) * 8);
      afr[i][1] = *(const bf16x8*)(Ah + r * 64 + ((4 | l4) ^ (r & 7)) * 8);
    }
    #pragma unroll
    for (int j = 0; j < 2; j++) {
      int r = brow + j * 16 + l15;
      bfr0[j][0] = *(const bf16x8*)(Bh + r * 64 + ((l4) ^ (r & 7)) * 8);
      bfr0[j][1] = *(const bf16x8*)(Bh + r * 64 + ((4 | l4) ^ (r & 7)) * 8);
    }
    if (more) {
      PJ_HALF(As[d ^ 1][0], Ap, 0, k0n)
      PJ_HALF(As[d ^ 1][1], Ap, 1, k0n)
    }
    __builtin_amdgcn_s_barrier();
    LGKM0;
    __builtin_amdgcn_s_setprio(1);
    #pragma unroll
    for (int ks = 0; ks < 2; ks++)
      #pragma unroll
      for (int i = 0; i < 4; i++)
        #pragma unroll
        for (int j = 0; j < 2; j++)
          acc[i][j] = MFMA16(afr[i][ks], bfr0[j][ks], acc[i][j]);
    __builtin_amdgcn_s_setprio(0);
    __builtin_amdgcn_s_barrier();

    // phase 1: read bf-hi; stage B halves of t+1
    #pragma unroll
    for (int j = 0; j < 2; j++) {
      int r = brow + (j + 2) * 16 + l15;
      bfr1[j][0] = *(const bf16x8*)(Bh + r * 64 + ((l4) ^ (r & 7)) * 8);
      bfr1[j][1] = *(const bf16x8*)(Bh + r * 64 + ((4 | l4) ^ (r & 7)) * 8);
    }
    if (more) {
      PJ_HALF(Bs[d ^ 1][0], Bp, 0, k0n)
      PJ_HALF(Bs[d ^ 1][1], Bp, 1, k0n)
    }
    __builtin_amdgcn_s_barrier();
    LGKM0;
    __builtin_amdgcn_s_setprio(1);
    #pragma unroll
    for (int ks = 0; ks < 2; ks++)
      #pragma unroll
      for (int i = 0; i < 4; i++)
        #pragma unroll
        for (int j = 0; j < 2; j++)
          acc[i][j + 2] = MFMA16(afr[i][ks], bfr1[j][ks], acc[i][j + 2]);
    __builtin_amdgcn_s_setprio(0);
    __builtin_amdgcn_s_barrier();

    // phase 2: read af-hi
    #pragma unroll
    for (int i = 0; i < 4; i++) {
      int r = 64 + i * 16 + l15;
      afr[i][0] = *(const bf16x8*)(Ah + r * 64 + ((l4) ^ (r & 7)) * 8);
      afr[i][1] = *(const bf16x8*)(Ah + r * 64 + ((4 | l4) ^ (r & 7)) * 8);
    }
    __builtin_amdgcn_s_barrier();
    LGKM0;
    __builtin_amdgcn_s_setprio(1);
    #pragma unroll
    for (int ks = 0; ks < 2; ks++)
      #pragma unroll
      for (int i = 0; i < 4; i++)
        #pragma unroll
        for (int j = 0; j < 2; j++)
          acc[i + 4][j + 2] = MFMA16(afr[i][ks], bfr1[j][ks], acc[i + 4][j + 2]);
    __builtin_amdgcn_s_setprio(0);
    __builtin_amdgcn_s_barrier();

    // phase 3: no reads; drain stages; flip
    __builtin_amdgcn_s_barrier();
    __builtin_amdgcn_s_setprio(1);
    #pragma unroll
    for (int ks = 0; ks < 2; ks++)
      #pragma unroll
      for (int i = 0; i < 4; i++)
        #pragma unroll
        for (int j = 0; j < 2; j++)
          acc[i + 4][j] = MFMA16(afr[i][ks], bfr0[j][ks], acc[i + 4][j]);
    __builtin_amdgcn_s_setprio(0);
    VM0;
    __builtin_amdgcn_s_barrier();
  }
#undef PJ_HALF

  // ---- epilogue: bias add; Q/K row-major store, V transposed store (fp8 / bf16) ----
  if (p < 2) {
    unsigned short* out = (p == 0) ? Qf : Kf;
    #pragma unroll
    for (int i = 0; i < 8; i++) {
      int m = m0 + wm * 128 + i * 16 + l4 * 4;
      #pragma unroll
      for (int j = 0; j < 4; j++) {
        int n = n0 + wn * 64 + j * 16 + l15;
        float bias = b4[p * 512 + n];
        #pragma unroll
        for (int r = 0; r < 4; r++)
          out[(size_t)(m + r) * 512 + n] = f2bf(acc[i][j][r] + bias);
      }
    }
  } else {
    #pragma unroll
    for (int i = 0; i < 8; i++) {
      int m = m0 + wm * 128 + i * 16 + l4 * 4;
      int bb = m >> 12, sb = m & 4095;
      #pragma unroll
      for (int j = 0; j < 4; j++) {
        int n = n0 + wn * 64 + j * 16 + l15;
        float bias = b4[2 * 512 + n];
        float v0 = acc[i][j][0] + bias, v1 = acc[i][j][1] + bias;
        float v2 = acc[i][j][2] + bias, v3 = acc[i][j][3] + bias;
        if (VfT) {
          ushort4 v;
          v.x = f2bf(v0); v.y = f2bf(v1); v.z = f2bf(v2); v.w = f2bf(v3);
          *(ushort4*)&VfT[((size_t)bb * CD + n) * SEQ + sb] = v;
        }
        if (Vf8)
          *(int*)&Vf8[((size_t)bb * CD + n) * SEQ + sb] = pk4_fp8(v0, v1, v2, v3);
      }
    }
  }
}

// ---------------- QK^T 256x256 tile, BK=64, dbuf LDS, 4-phase; L2-blocked decode --------
// Concurrent 32 blocks/XCD cover a 4qt x 8kt super-tile: K 2MB + Q 1MB < 4MB L2.
__global__ __launch_bounds__(512, 2) void gemm_qk256(
    const unsigned short* __restrict__ Qf, const unsigned short* __restrict__ Kf,
    unsigned char* __restrict__ P8, float* __restrict__ partials,
    int bbase, int nbat) {
  __shared__ unsigned short As[2][2][128 * 64];   // 64 KB
  __shared__ unsigned short Bs[2][2][128 * 64];   // 64 KB
  __shared__ float ssum[2][4][4][16];             // [wm][wn][j][l15]

  const int tid = threadIdx.x;
  const int wid = tid >> 6, lane = tid & 63;
  const int l15 = lane & 15, l4 = lane >> 4;
  const int wm = wid >> 2, wn = wid & 3;

  const int id = blockIdx.x;
  const int xcd = id & 7;
  int z, qt, kt;
  if (nbat == 4) {
    z = xcd >> 1;
    int w = id >> 3;                     // 0..127
    int grp = w >> 5, sub = w & 31;      // 4 groups of 32 (concurrent per XCD)
    qt = ((xcd & 1) << 3) | ((grp >> 1) << 2) | (sub >> 3);   // 0..15
    kt = ((grp & 1) << 3) | (sub & 7);                         // 0..15
  } else {
    z = 0;
    int w = id >> 3;                     // 0..31
    qt = (xcd << 1) | (w >> 4);
    kt = w & 15;
  }
  const int b = bbase + z;
  const int m0 = kt * 256;               // k rows
  const int n0 = qt * 256;               // q rows

  const unsigned short* Ap = Kf + ((size_t)b * SEQ + m0) * CD;
  const unsigned short* Bp = Qf + ((size_t)b * SEQ + n0) * CD;

#define QK_HALF(DST, SRC, HALF, K0)                                           \
  _Pragma("unroll")                                                           \
  for (int i_ = 0; i_ < 2; i_++) {                                            \
    int sg = i_ * 512 + tid;                                                  \
    int row = sg >> 3, kc = sg & 7;                                           \
    int kcs = kc ^ (row & 7);                                                 \
    gload_lds16(SRC + (size_t)((HALF) * 128 + row) * CD + (K0) + kcs * 8,     \
                &DST[sg * 8]);                                                \
  }

  f32x4 acc[8][4];
  #pragma unroll
  for (int i = 0; i < 8; i++)
    #pragma unroll
    for (int j = 0; j < 4; j++) acc[i][j] = (f32x4){0.f, 0.f, 0.f, 0.f};

  QK_HALF(As[0][0], Ap, 0, 0)
  QK_HALF(As[0][1], Ap, 1, 0)
  QK_HALF(Bs[0][0], Bp, 0, 0)
  QK_HALF(Bs[0][1], Bp, 1, 0)
  VM0;
  __builtin_amdgcn_s_barrier();

  bf16x8 afr[4][2], bfr0[2][2], bfr1[2][2];
  const int bh = wn >> 1;
  const int brow = (wn & 1) * 64;

  for (int t = 0; t < 8; t++) {
    const int d = t & 1;
    const unsigned short* Ah = As[d][wm];
    const unsigned short* Bh = Bs[d][bh];
    const int k0n = (t + 1) * 64;
    const bool more = (t < 7);

    // phase 0
    #pragma unroll
    for (int i = 0; i < 4; i++) {
      int r = i * 16 + l15;
      afr[i][0] = *(const bf16x8*)(Ah + r * 64 + ((l4) ^ (r & 7)) * 8);
      afr[i][1] = *(const bf16x8*)(Ah + r * 64 + ((4 | l4) ^ (r & 7)) * 8);
    }
    #pragma unroll
    for (int j = 0; j < 2; j++) {
      int r = brow + j * 16 + l15;
      bfr0[j][0] = *(const bf16x8*)(Bh + r * 64 + ((l4) ^ (r & 7)) * 8);
      bfr0[j][1] = *(const bf16x8*)(Bh + r * 64 + ((4 | l4) ^ (r & 7)) * 8);
    }
    if (more) {
      QK_HALF(As[d ^ 1][0], Ap, 0, k0n)
      QK_HALF(As[d ^ 1][1], Ap, 1, k0n)
    }
    __builtin_amdgcn_s_barrier();
    LGKM0;
    __builtin_amdgcn_s_setprio(1);
    #pragma unroll
    for (int ks = 0; ks < 2; ks++)
      #pragma unroll
      for (int i = 0; i < 4; i++)
        #pragma unroll
        for (int j = 0; j < 2; j++)
          acc[i][j] = MFMA16(afr[i][ks], bfr0[j][ks], acc[i][j]);
    __builtin_amdgcn_s_setprio(0);
    __builtin_amdgcn_s_barrier();

    // phase 1
    #pragma unroll
    for (int j = 0; j < 2; j++) {
      int r = brow + (j + 2) * 16 + l15;
      bfr1[j][0] = *(const bf16x8*)(Bh + r * 64 + ((l4) ^ (r & 7)) * 8);
      bfr1[j][1] = *(const bf16x8*)(Bh + r * 64 + ((4 | l4) ^ (r & 7)) * 8);
    }
    if (more) {
      QK_HALF(Bs[d ^ 1][0], Bp, 0, k0n)
      QK_HALF(Bs[d ^ 1][1], Bp, 1, k0n)
    }
    __builtin_amdgcn_s_barrier();
    LGKM0;
    __builtin_amdgcn_s_setprio(1);
    #pragma unroll
    for (int ks = 0; ks < 2; ks++)
      #pragma unroll
      for (int i = 0; i < 4; i++)
        #pragma unroll
        for (int j = 0; j < 2; j++)
          acc[i][j + 2] = MFMA16(afr[i][ks], bfr1[j][ks], acc[i][j + 2]);
    __builtin_amdgcn_s_setprio(0);
    __builtin_amdgcn_s_barrier();

    // phase 2
    #pragma unroll
    for (int i = 0; i < 4; i++) {
      int r = 64 + i * 16 + l15;
      afr[i][0] = *(const bf16x8*)(Ah + r * 64 + ((l4) ^ (r & 7)) * 8);
      afr[i][1] = *(const bf16x8*)(Ah + r * 64 + ((4 | l4) ^ (r & 7)) * 8);
    }
    __builtin_amdgcn_s_barrier();
    LGKM0;
    __builtin_amdgcn_s_setprio(1);
    #pragma unroll
    for (int ks = 0; ks < 2; ks++)
      #pragma unroll
      for (int i = 0; i < 4; i++)
        #pragma unroll
        for (int j = 0; j < 2; j++)
          acc[i + 4][j + 2] = MFMA16(afr[i][ks], bfr1[j][ks], acc[i + 4][j + 2]);
    __builtin_amdgcn_s_setprio(0);
    __builtin_amdgcn_s_barrier();

    // phase 3
    __builtin_amdgcn_s_barrier();
    __builtin_amdgcn_s_setprio(1);
    #pragma unroll
    for (int ks = 0; ks < 2; ks++)
      #pragma unroll
      for (int i = 0; i < 4; i++)
        #pragma unroll
        for (int j = 0; j < 2; j++)
          acc[i + 4][j] = MFMA16(afr[i][ks], bfr0[j][ks], acc[i + 4][j]);
    __builtin_amdgcn_s_setprio(0);
    VM0;
    __builtin_amdgcn_s_barrier();
  }
#undef QK_HALF

  // ---- epilogue: exp2, store P fp8 (4B), row partial sums ----
  unsigned char* Pz = P8 + (size_t)z * SEQ * SEQ;
  float sj[4] = {0.f, 0.f, 0.f, 0.f};
  #pragma unroll
  for (int i = 0; i < 8; i++) {
    int m = m0 + wm * 128 + i * 16 + l4 * 4;      // k (4 consecutive)
    #pragma unroll
    for (int j = 0; j < 4; j++) {
      int n = n0 + wn * 64 + j * 16 + l15;        // q
      float p0 = __builtin_amdgcn_exp2f(acc[i][j][0]);
      float p1 = __builtin_amdgcn_exp2f(acc[i][j][1]);
      float p2 = __builtin_amdgcn_exp2f(acc[i][j][2]);
      float p3 = __builtin_amdgcn_exp2f(acc[i][j][3]);
      sj[j] += (p0 + p1) + (p2 + p3);
      *(int*)&Pz[(size_t)n * SEQ + m] = pk4_fp8(p0, p1, p2, p3);
    }
  }
  #pragma unroll
  for (int j = 0; j < 4; j++) {
    float s = sj[j];
    s += __shfl_xor(s, 16, 64);
    s += __shfl_xor(s, 32, 64);
    if (lane < 16) ssum[wm][wn][j][l15] = s;
  }
  __syncthreads();
  if (tid < 256) {
    int wn_ = tid >> 6, j_ = (tid >> 4) & 3, l_ = tid & 15;
    float s = ssum[0][wn_][j_][l_] + ssum[1][wn_][j_][l_];
    partials[((size_t)z * SEQ + n0 + tid) * 16 + kt] = s;
  }
}

// ---------------- l reduce: linv[q] = 1 / sum_16 partials[q][.] ----------------
__global__ __launch_bounds__(256) void reduce_l(
    const float* __restrict__ partials, float* __restrict__ linv) {
  int i = blockIdx.x * 256 + threadIdx.x;
  const float* p = partials + (size_t)i * 16;
  float s = 0.f;
  #pragma unroll
  for (int j = 0; j < 16; j++) s += p[j];
  linv[i] = 1.0f / s;
}

// ---------------- PV fp8 GEMM: 128x64 tile, 4 waves, BK=128 fp8, 2-barrier ----------------
__global__ __launch_bounds__(256) void gemm_pv8(
    const unsigned char* __restrict__ Vf8, const unsigned char* __restrict__ P8,
    const float* __restrict__ linv, unsigned short* __restrict__ Ao,
    int bbase, int nbat) {
  __shared__ unsigned char As[128 * 128];   // 16 KB
  __shared__ unsigned char Bs[64 * 128];    // 8 KB
  const int tid = threadIdx.x;
  const int wid = tid >> 6, lane = tid & 63;
  const int l15 = lane & 15, l4 = lane >> 4;
  const int wr = wid >> 1, wc = wid & 1;

  const int id = blockIdx.x;
  const int xcd = id & 7;
  int z, qt, ct;
  if (nbat == 4) {
    z = xcd >> 1;
    int w = id >> 3;                      // 0..127
    qt = ((xcd & 1) << 5) | (w >> 2);     // 0..63
    ct = w & 3;
  } else {
    z = 0;
    int w = id >> 3;                      // 0..31
    qt = (xcd << 3) | (w >> 2);
    ct = w & 3;
  }
  const int b = bbase + z;
  const int n0 = qt * 64, m0 = ct * 128;

  const unsigned char* Ap = Vf8 + ((size_t)b * CD + m0) * SEQ;
  const unsigned char* Bp = P8 + (size_t)z * SEQ * SEQ + (size_t)n0 * SEQ;

  f32x4 acc[4][2];
  #pragma unroll
  for (int i = 0; i < 4; i++) {
    acc[i][0] = (f32x4){0.f, 0.f, 0.f, 0.f};
    acc[i][1] = (f32x4){0.f, 0.f, 0.f, 0.f};
  }

  for (int k0 = 0; k0 < SEQ; k0 += 128) {
    #pragma unroll
    for (int i = 0; i < 4; i++) {
      int sg = i * 256 + tid;
      int row = sg >> 3, kc = sg & 7;
      int kcs = kc ^ (row & 7);
      gload_lds16(Ap + (size_t)row * SEQ + k0 + kcs * 16, As + sg * 16);
    }
    #pragma unroll
    for (int i = 0; i < 2; i++) {
      int sg = i * 256 + tid;
      int row = sg >> 3, kc = sg & 7;
      int kcs = kc ^ (row & 7);
      gload_lds16(Bp + (size_t)row * SEQ + k0 + kcs * 16, Bs + sg * 16);
    }
    __syncthreads();
    #pragma unroll
    for (int ks = 0; ks < 4; ks++) {
      i64frag af[4], bf[2];
      const int ch = ks * 2 + (l4 >> 1);
      const int hb = (l4 & 1) * 8;
      #pragma unroll
      for (int i = 0; i < 4; i++) {
        int ra = wr * 64 + i * 16 + l15;
        af[i] = *(const i64frag*)(As + ra * 128 + (ch ^ (ra & 7)) * 16 + hb);
      }
      #pragma unroll
      for (int j = 0; j < 2; j++) {
        int rb = wc * 32 + j * 16 + l15;
        bf[j] = *(const i64frag*)(Bs + rb * 128 + (ch ^ (rb & 7)) * 16 + hb);
      }
      #pragma unroll
      for (int i = 0; i < 4; i++)
        #pragma unroll
        for (int j = 0; j < 2; j++)
          acc[i][j] = MFMA8(af[i], bf[j], acc[i][j]);
    }
    __syncthreads();
  }

  #pragma unroll
  for (int j = 0; j < 2; j++) {
    int n = n0 + wc * 32 + j * 16 + l15;        // q
    float inv = linv[(size_t)z * SEQ + n];
    #pragma unroll
    for (int i = 0; i < 4; i++) {
      int m = m0 + wr * 64 + i * 16 + l4 * 4;   // c
      ushort4 o4;
      o4.x = f2bf(acc[i][j][0] * inv);
      o4.y = f2bf(acc[i][j][1] * inv);
      o4.z = f2bf(acc[i][j][2] * inv);
      o4.w = f2bf(acc[i][j][3] * inv);
      *(ushort4*)&Ao[((size_t)b * SEQ + n) * CD + m] = o4;
    }
  }
}

// ---------------- flash attention v4 (fallback when workspace is small) ----------------
#define SECTION(T, VRC, VRP, DOPV)                                              \
  {                                                                             \
    const int t_ = (T);                                                         \
    const unsigned short* vt_ = vbase + t_ * 32;                                \
    _Pragma("unroll")                                                           \
    for (int i = 0; i < 8; i++)                                                 \
      VRC[i] = *(const bf16x8*)(vt_ + (size_t)i * 16 * SEQ);                    \
    f32x4 sf = (f32x4){0.f, 0.f, 0.f, 0.f};                                     \
    __builtin_amdgcn_s_setprio(1);                                              \
    {                                                                           \
      const char* krow = (const char*)(Ks + (size_t)(t_ & 3) * 16384) +         \
                         (s * 16 + l15) * 1024;                                 \
      const int kswz = (l15 & 7) << 4;                                          \
      _Pragma("unroll")                                                         \
      for (int ck = 0; ck < 16; ck++) {                                         \
        bf16x8 kf = *(const bf16x8*)(krow + ((ck * 64 + l4 * 16) ^ kswz));      \
        sf = MFMA16(kf, qreg[ck], sf);                                          \
      }                                                                         \
    }                                                                           \
    if (DOPV) {                                                                 \
      _Pragma("unroll")                                                         \
      for (int jf = 0; jf < 2; jf++) {                                          \
        int qv = qw * 32 + jf * 16 + l15;                                       \
        bf16x8 pb = *(const bf16x8*)((const char*)Ps + ((t_ + 1) & 1) * 4096 +  \
                                     qv * 64 +                                  \
                                     ((l4 * 16) ^ (((qv >> 1) & 3) << 4)));     \
        _Pragma("unroll")                                                       \
        for (int i = 0; i < 8; i++)                                             \
          acc[i][jf] = MFMA16(VRP[i], pb, acc[i][jf]);                          \
      }                                                                         \
    }                                                                           \
    __builtin_amdgcn_s_setprio(0);                                              \
    {                                                                           \
      float p0 = __builtin_amdgcn_exp2f(sf[0]);                                 \
      float p1 = __builtin_amdgcn_exp2f(sf[1]);                                 \
      float p2 = __builtin_amdgcn_exp2f(sf[2]);                                 \
      float p3 = __builtin_amdgcn_exp2f(sf[3]);                                 \
      l_acc[0] += p0; l_acc[1] += p1; l_acc[2] += p2; l_acc[3] += p3;           \
      ushort4 pk;                                                               \
      pk.x = f2bf(p0); pk.y = f2bf(p1); pk.z = f2bf(p2); pk.w = f2bf(p3);       \
      int q_ = g * 16 + l15;                                                    \
      int off = (t_ & 1) * 4096 + q_ * 64 +                                     \
                ((s * 32 + l4 * 8) ^ (((q_ >> 1) & 3) << 4));                   \
      *(ushort4*)((char*)Ps + off) = pk;                                        \
    }                                                                           \
    {                                                                           \
      int tt = (t_ + 2 < 128) ? t_ + 2 : 127;                                   \
      const unsigned short* kn = kbT + (size_t)tt * 32 * CD;                    \
      unsigned short* kdst = Ks + (size_t)((t_ + 2) & 3) * 16384;               \
      _Pragma("unroll")                                                         \
      for (int i = 0; i < 4; i++) {                                             \
        int slot = i * 512 + tid;                                               \
        int row = slot >> 6, kc = slot & 63;                                    \
        int kcs = kc ^ (row & 7);                                               \
        gload_lds16(kn + (size_t)row * CD + kcs * 8,                            \
                    kdst + (size_t)(i * 512 + wid * 64) * 8);                   \
      }                                                                         \
    }                                                                           \
    LGKM0;                                                                      \
    VMC12;                                                                      \
    __builtin_amdgcn_s_barrier();                                               \
  }

__global__ __launch_bounds__(512, 2) void flash_attn(
    const unsigned short* __restrict__ Qf, const unsigned short* __restrict__ Kf,
    const unsigned short* __restrict__ VfT, unsigned short* __restrict__ Ao) {
  __shared__ unsigned short Ks[4 * 32 * 512];
  __shared__ unsigned short Ps[2 * 64 * 32];
  __shared__ float ssum[4][2][16];

  const int tid = threadIdx.x;
  const int wid = tid >> 6, lane = tid & 63;
  const int l15 = lane & 15, l4 = lane >> 4;
  const int s = wid & 1, g = wid >> 1;
  const int cw = wid & 3, qw = wid >> 2;

  const int id = blockIdx.x;
  const int xcd = id & 7;
  const int b = xcd >> 1;
  const int q0 = ((id >> 3) + ((xcd & 1) << 5)) * 64;

  const unsigned short* kbT = Kf + (size_t)b * SEQ * CD;
  const unsigned short* vbase = VfT + ((size_t)b * CD + cw * 128 + l15) * SEQ + l4 * 8;

  #pragma unroll
  for (int tt = 0; tt < 2; tt++) {
    const unsigned short* kn = kbT + (size_t)tt * 32 * CD;
    unsigned short* kdst = Ks + (size_t)tt * 16384;
    #pragma unroll
    for (int i = 0; i < 4; i++) {
      int slot = i * 512 + tid;
      int row = slot >> 6, kc = slot & 63;
      int kcs = kc ^ (row & 7);
      gload_lds16(kn + (size_t)row * CD + kcs * 8, kdst + (size_t)(i * 512 + wid * 64) * 8);
    }
  }

  bf16x8 qreg[16];
  {
    const unsigned short* qp = Qf + ((size_t)b * SEQ + q0 + g * 16 + l15) * CD + l4 * 8;
    #pragma unroll
    for (int ck = 0; ck < 16; ck++) qreg[ck] = *(const bf16x8*)(qp + ck * 32);
  }

  f32x4 acc[8][2];
  #pragma unroll
  for (int i = 0; i < 8; i++) {
    acc[i][0] = (f32x4){0.f, 0.f, 0.f, 0.f};
    acc[i][1] = (f32x4){0.f, 0.f, 0.f, 0.f};
  }
  f32x4 l_acc = (f32x4){0.f, 0.f, 0.f, 0.f};

  bf16x8 vrA[8], vrB[8];

  VM0;
  __builtin_amdgcn_s_barrier();

  SECTION(0, vrA, vrB, 0);
  for (int t = 1; t < 127; t += 2) {
    SECTION(t, vrB, vrA, 1);
    SECTION(t + 1, vrA, vrB, 1);
  }
  SECTION(127, vrB, vrA, 1);

  #pragma unroll
  for (int jf = 0; jf < 2; jf++) {
    int qv = qw * 32 + jf * 16 + l15;
    bf16x8 pb = *(const bf16x8*)((const char*)Ps + 4096 + qv * 64 +
                                 ((l4 * 16) ^ (((qv >> 1) & 3) << 4)));
    #pragma unroll
    for (int i = 0; i < 8; i++)
      acc[i][jf] = MFMA16(vrB[i], pb, acc[i][jf]);
  }

  float strip = (l_acc[0] + l_acc[1]) + (l_acc[2] + l_acc[3]);
  strip += __shfl_xor(strip, 16, 64);
  strip += __shfl_xor(strip, 32, 64);
  __syncthreads();
  if (lane < 16) ssum[g][s][l15] = strip;
  __syncthreads();

  #pragma unroll
  for (int jf = 0; jf < 2; jf++) {
    int gq = qw * 2 + jf;
    float inv = 1.0f / (ssum[gq][0][l15] + ssum[gq][1][l15]);
    #pragma unroll
    for (int i = 0; i < 8; i++) {
      int c0 = cw * 128 + i * 16 + l4 * 4;
      ushort4 o4;
      o4.x = f2bf(acc[i][jf][0] * inv);
      o4.y = f2bf(acc[i][jf][1] * inv);
      o4.z = f2bf(acc[i][jf][2] * inv);
      o4.w = f2bf(acc[i][jf][3] * inv);
      *(ushort4*)&Ao[((size_t)b * SEQ + q0 + qw * 32 + jf * 16 + l15) * CD + c0] = o4;
    }
  }
}

// ---------------- output projection: out[b][o][s] fp32 ----------------
__global__ __launch_bounds__(256) void gemm_out(
    const unsigned short* __restrict__ W4, const float* __restrict__ b4,
    const unsigned short* __restrict__ Ao, float* __restrict__ out) {
  __shared__ unsigned short As[128 * 64], Bs[128 * 64];
  const int b = blockIdx.z;
  const int n0 = blockIdx.x * 128, m0 = blockIdx.y * 128;
  f32x4 acc[4][4];
  #pragma unroll
  for (int i = 0; i < 4; i++)
    #pragma unroll
    for (int j = 0; j < 4; j++) acc[i][j] = (f32x4){0.f, 0.f, 0.f, 0.f};
  gemm_core(W4 + ((size_t)3 * 512 + m0) * 512, Ao + ((size_t)b * SEQ + n0) * 512, As, Bs, acc);

  const int t = threadIdx.x;
  const int wid = t >> 6, lane = t & 63;
  const int l15 = lane & 15, l4 = lane >> 4;
  const int wr = wid >> 1, wc = wid & 1;
  #pragma unroll
  for (int i = 0; i < 4; i++) {
    int m = m0 + wr * 64 + i * 16 + l4 * 4;
    #pragma unroll
    for (int j = 0; j < 4; j++) {
      int n = n0 + wc * 64 + j * 16 + l15;
      #pragma unroll
      for (int r = 0; r < 4; r++)
        out[((size_t)b * CD + m + r) * SEQ + n] = acc[i][j][r] + b4[3 * 512 + m + r];
    }
  }
}

extern "C" void kernel_launch(void* const* d_in, const int* in_sizes, int n_in,
                              void* d_out, int out_size, void* d_ws, size_t ws_size,
                              hipStream_t stream) {
  (void)in_sizes; (void)n_in; (void)out_size;
  const float* q  = (const float*)d_in[0];
  const float* Wq = (const float*)d_in[1];
  const float* bq = (const float*)d_in[2];
  const float* Wk = (const float*)d_in[3];
  const float* bk = (const float*)d_in[4];
  const float* Wv = (const float*)d_in[5];
  const float* bv = (const float*)d_in[6];
  const float* Wo = (const float*)d_in[7];
  const float* bo = (const float*)d_in[8];
  float* out = (float*)d_out;

  char* ws = (char*)d_ws;
  const size_t MB = (size_t)1 << 20;
  unsigned short* qT  = (unsigned short*)(ws);            // 16MB (reused as Ao)
  unsigned short* Qf  = (unsigned short*)(ws + 16 * MB);
  unsigned short* Kf  = (unsigned short*)(ws + 32 * MB);
  unsigned short* VfT = (unsigned short*)(ws + 48 * MB);  // bf16 V (flash fallback only)
  unsigned short* Ao = qT;

  if (ws_size >= 134 * MB) {
    // fp8 path, all 4 batches: P8 overlays VfT region (dead on this path)
    unsigned char* P8    = (unsigned char*)(ws + 48 * MB);   // 64MB -> 48..112
    unsigned short* W4   = (unsigned short*)(ws + 112 * MB); // 2MB
    float* b4            = (float*)(ws + 114 * MB);          // 8KB
    unsigned char* Vf8   = (unsigned char*)(ws + 115 * MB);  // 8MB
    float* partials      = (float*)(ws + 123 * MB);          // 1MB
    float* linv          = (float*)(ws + 124 * MB + 512 * 1024);

    convert_w<<<4096, 256, 0, stream>>>(Wq, Wk, Wv, Wo, bq, bk, bv, bo, W4, b4);
    transpose_q<<<dim3(64, 8, 4), 256, 0, stream>>>(q, qT);
    gemm_proj256<<<384, 512, 0, stream>>>(qT, W4, b4, Qf, Kf, (unsigned short*)nullptr, Vf8);
    gemm_qk256<<<1024, 512, 0, stream>>>(Qf, Kf, P8, partials, 0, 4);
    reduce_l<<<64, 256, 0, stream>>>(partials, linv);
    gemm_pv8<<<1024, 256, 0, stream>>>(Vf8, P8, linv, Ao, 0, 4);
    gemm_out<<<dim3(32, 4, 4), 256, 0, stream>>>(W4, b4, Ao, out);
  } else if (ws_size >= 101 * MB) {
    // fp8 path, per-batch: P8 (16MB) overlays VfT region
    unsigned char* P8    = (unsigned char*)(ws + 48 * MB);   // 16MB -> 48..64
    unsigned short* W4   = (unsigned short*)(ws + 64 * MB);  // 2MB
    float* b4            = (float*)(ws + 66 * MB);           // 8KB
    unsigned char* Vf8   = (unsigned char*)(ws + 67 * MB);   // 8MB -> 67..75
    float* partials      = (float*)(ws + 75 * MB);           // 256KB
    float* linv          = (float*)(ws + 76 * MB);           // 16KB

    convert_w<<<4096, 256, 0, stream>>>(Wq, Wk, Wv, Wo, bq, bk, bv, bo, W4, b4);
    transpose_q<<<dim3(64, 8, 4), 256, 0, stream>>>(q, qT);
    gemm_proj256<<<384, 512, 0, stream>>>(qT, W4, b4, Qf, Kf, (unsigned short*)nullptr, Vf8);
    for (int bb = 0; bb < 4; ++bb) {
      gemm_qk256<<<256, 512, 0, stream>>>(Qf, Kf, P8, partials, bb, 1);
      reduce_l<<<16, 256, 0, stream>>>(partials, linv);
      gemm_pv8<<<256, 256, 0, stream>>>(Vf8, P8, linv, Ao, bb, 1);
    }
    gemm_out<<<dim3(32, 4, 4), 256, 0, stream>>>(W4, b4, Ao, out);
  } else {
    // bf16 flash fallback
    unsigned short* W4 = (unsigned short*)(ws + 64 * MB);
    float* b4          = (float*)(ws + 66 * MB);
    convert_w<<<4096, 256, 0, stream>>>(Wq, Wk, Wv, Wo, bq, bk, bv, bo, W4, b4);
    transpose_q<<<dim3(64, 8, 4), 256, 0, stream>>>(q, qT);
    gemm_proj256<<<384, 512, 0, stream>>>(qT, W4, b4, Qf, Kf, VfT, (unsigned char*)nullptr);
    flash_attn<<<256, 512, 0, stream>>>(Qf, Kf, VfT, Ao);
    gemm_out<<<dim3(32, 4, 4), 256, 0, stream>>>(W4, b4, Ao, out);
  }
}